// Round 8
// baseline (676.324 us; speedup 1.0000x reference)
//
#include <hip/hip_runtime.h>
#include <hip/hip_bf16.h>
#include <cstdint>
#include <cstddef>

#define N_TOK 8192
#define DIM   2048
#define HID   2048
#define NE    8

typedef _Float16 half8  __attribute__((ext_vector_type(8)));
typedef _Float16 half4v __attribute__((ext_vector_type(4)));
typedef float    floatx4 __attribute__((ext_vector_type(4)));

#define BARR  __builtin_amdgcn_s_barrier()
#define SB0   __builtin_amdgcn_sched_barrier(0)

__device__ inline void gload_lds16(const void* g, void* l) {
    __builtin_amdgcn_global_load_lds(
        (const __attribute__((address_space(1))) unsigned int*)g,
        (__attribute__((address_space(3))) unsigned int*)l, 16, 0, 0);
}

__device__ __forceinline__ floatx4 MF(half8 a, half8 b, floatx4 c) {
    return __builtin_amdgcn_mfma_f32_16x16x32_f16(a, b, c, 0, 0, 0);
}

// ---------------- fused W1+W2 [E][R][C] fp32 -> [E][C][R] fp16 ----------------
__global__ __launch_bounds__(256) void k_prep(const float* __restrict__ W1,
                                              const float* __restrict__ W2,
                                              _Float16* __restrict__ w1t,
                                              _Float16* __restrict__ w2t) {
    __shared__ float tile[64][65];
    int z = blockIdx.z;
    const float* in = (z < 8) ? W1 : W2;
    _Float16* out   = (z < 8) ? w1t : w2t;
    int e  = z & 7;
    int r0 = blockIdx.y * 64;
    int c0 = blockIdx.x * 64;
    int tc = threadIdx.x & 63, tr = threadIdx.x >> 6;
    const float* ip = in + ((size_t)e * 2048 + r0) * 2048 + c0;
#pragma unroll
    for (int i = 0; i < 16; i++)
        tile[tr + i * 4][tc] = ip[(size_t)(tr + i * 4) * 2048 + tc];
    __syncthreads();
    _Float16* op = out + ((size_t)e * 2048 + c0) * 2048 + r0;
#pragma unroll
    for (int i = 0; i < 16; i++) {
        int cc = tr + i * 4;
        op[(size_t)cc * 2048 + tc] = (_Float16)tile[tc][cc];
    }
}

// ---------------- gate: fp64-accum logits, top-2, softmax; fuses x->fp16 ----------------
__global__ __launch_bounds__(256) void k_gate(const float* __restrict__ x,
                                              const float* __restrict__ Wg,
                                              const float* __restrict__ bg,
                                              _Float16* __restrict__ xh,
                                              int* __restrict__ te, float* __restrict__ tw,
                                              int* __restrict__ counts) {
    __shared__ float wgs[NE * DIM]; // 64 KB, transposed [e][d]
    __shared__ int lcnt[NE];
    if (threadIdx.x < NE) lcnt[threadIdx.x] = 0;
    for (int i = threadIdx.x; i < NE * DIM; i += 256)
        wgs[(i & 7) * DIM + (i >> 3)] = Wg[i];
    __syncthreads();
    int wv = threadIdx.x >> 6, l = threadIdx.x & 63;
#pragma unroll 1
    for (int it = 0; it < 4; ++it) {
        int t = blockIdx.x * 16 + wv * 4 + it;
        const float* xr = x + (size_t)t * DIM;
        double acc[NE] = {0, 0, 0, 0, 0, 0, 0, 0};
#pragma unroll 2
        for (int i = 0; i < 8; i++) {
            int d0 = i * 256 + l * 4;
            float4 xv = *(const float4*)(xr + d0);
            half4v hv;
            hv[0] = (_Float16)xv.x; hv[1] = (_Float16)xv.y;
            hv[2] = (_Float16)xv.z; hv[3] = (_Float16)xv.w;
            *(half4v*)(xh + (size_t)t * DIM + d0) = hv;
#pragma unroll
            for (int e = 0; e < NE; e++) {
                float4 w4 = *(const float4*)(wgs + e * DIM + d0);
                acc[e] += (double)xv.x * w4.x + (double)xv.y * w4.y +
                          (double)xv.z * w4.z + (double)xv.w * w4.w;
            }
        }
#pragma unroll
        for (int e = 0; e < NE; e++) {
            double v = acc[e];
            v += __shfl_xor(v, 32, 64); v += __shfl_xor(v, 16, 64);
            v += __shfl_xor(v, 8, 64);  v += __shfl_xor(v, 4, 64);
            v += __shfl_xor(v, 2, 64);  v += __shfl_xor(v, 1, 64);
            acc[e] = v;
        }
        if (l == 0) {
            double best0 = -1e300, best1 = -1e300; int i0 = 0, i1 = 0;
#pragma unroll
            for (int e = 0; e < NE; e++) {
                double lg = acc[e] + (double)bg[e];
                if (lg > best0) { best1 = best0; i1 = i0; best0 = lg; i0 = e; }
                else if (lg > best1) { best1 = lg; i1 = e; }
            }
            float d  = expf((float)(best1 - best0));
            float w0 = 1.f / (1.f + d), w1 = d / (1.f + d);
            te[2 * t] = i0; te[2 * t + 1] = i1;
            tw[2 * t] = w0; tw[2 * t + 1] = w1;
            atomicAdd(&lcnt[i0], 1);
            atomicAdd(&lcnt[i1], 1);
        }
    }
    __syncthreads();
    if (threadIdx.x < NE) atomicAdd(&counts[threadIdx.x], lcnt[threadIdx.x]);
}

// ---------------- tiny scan ----------------
__global__ void k_scan(const int* __restrict__ counts, int* __restrict__ offs,
                       int* __restrict__ fill) {
    if (threadIdx.x == 0 && blockIdx.x == 0) {
        int s = 0;
        for (int e = 0; e < NE; e++) { offs[e] = s; s += counts[e]; fill[e] = 0; }
        offs[NE] = s;
    }
}

// ---------------- scatter tokens to expert lists ----------------
__global__ __launch_bounds__(256) void k_scatter(const int* __restrict__ te,
                                                 const float* __restrict__ tw,
                                                 const int* __restrict__ offs,
                                                 int* __restrict__ fill,
                                                 int* __restrict__ ltok,
                                                 float* __restrict__ lw,
                                                 int* __restrict__ tslot) {
    int t = blockIdx.x * blockDim.x + threadIdx.x;
    if (t >= N_TOK) return;
#pragma unroll
    for (int k = 0; k < 2; k++) {
        int e = te[2 * t + k];
        int p = atomicAdd(&fill[e], 1);
        int idx = offs[e] + p;
        ltok[idx] = t; lw[idx] = tw[2 * t + k]; tslot[2 * t + k] = idx;
    }
}

// ====== quadrant-pipelined GEMM: BM=BN=256, BK=64, 4 phases/tile, read-ahead ======
// 512 thr = 8 waves (2m x 4n); wave tile 128x64; acc[8][4] of 16x16x32_f16.
// LDS: As[2][256][64] + Bs[2][256][64] = 128 KB; tile t -> buf t&1.
// Operand regs per tile: aLo(fm0-3), aHi(fm4-7), bLo(fn0-1), bHi(fn2-3), each x2 kk.
// Phase ledger (per tile t, steady state; reads issued >=1 phase before use):
//  ph0: read bHi(t)[4]   ; lgkmcnt(4)  -> aLo,bLo(t) retired ; MFMA Q00 (fm0-3 x fn0-1)
//  ph1: read aHi(t)[8]   ; lgkmcnt(8)  -> bHi retired        ; MFMA Q01 (fm0-3 x fn2-3)
//  ph2: lgkmcnt(0) -> aHi retired      ; MFMA Q10 (fm4-7 x fn0-1)
//       BARR (all waves' buf-t reads retired -> consumed)
//       stage tile t+2 -> buf t (8 gload_lds)
//       vmcnt(8) -> forces tile t+1's batch (issued 1 tile ago), t+2's 8 stay in flight
//       BARR (buf t+1 ready)
//  ph3: read aLo,bLo(t+1)[12] from buf t+1 (no wait; next ph0's lgkmcnt(4) covers)
//       MFMA Q11 (fm4-7 x fn2-3)
// Every lgkmcnt gate is followed by sched_barrier(0) (rule 18: stop MFMA hoisting).
// XOR swizzle both-sides (rule 21): physical 16B chunk = logical ^ (row&7).

#define PRIO1 __builtin_amdgcn_s_setprio(1)
#define PRIO0 __builtin_amdgcn_s_setprio(0)

template<int MODE>  // 0: full; 1: t=NT-2 (no stage, vmcnt(0)); 2: last tile
__device__ __forceinline__ void tileQ(
    _Float16* As, _Float16* Bs, int bufR, int kt2,
    const _Float16* aS0, const _Float16* aS1, const _Float16* aS2, const _Float16* aS3,
    const _Float16* bS0, const _Float16* bS1, const _Float16* bS2, const _Float16* bS3,
    int ldA, int sdB, int rA, int rB, int cbo0, int cbo1,
    half8 (&aLo)[4][2], half8 (&aHi)[4][2], half8 (&bLo)[2][2], half8 (&bHi)[2][2],
    floatx4 (&acc)[8][4])
{
    const _Float16* Ab  = As + bufR * 16384;
    const _Float16* Bb  = Bs + bufR * 16384;
    const _Float16* AbN = As + (bufR ^ 1) * 16384;
    const _Float16* BbN = Bs + (bufR ^ 1) * 16384;

    // ---- ph0 ----
#pragma unroll
    for (int fn = 0; fn < 2; fn++) {
        bHi[fn][0] = *(const half8*)(Bb + rB + (2 + fn) * 1024 + cbo0);
        bHi[fn][1] = *(const half8*)(Bb + rB + (2 + fn) * 1024 + cbo1);
    }
    asm volatile("s_waitcnt lgkmcnt(4)" ::: "memory"); SB0;
    PRIO1;
#pragma unroll
    for (int fm = 0; fm < 4; fm++)
#pragma unroll
        for (int fn = 0; fn < 2; fn++) {
            acc[fm][fn] = MF(aLo[fm][0], bLo[fn][0], acc[fm][fn]);
            acc[fm][fn] = MF(aLo[fm][1], bLo[fn][1], acc[fm][fn]);
        }
    PRIO0;

    // ---- ph1 ----
#pragma unroll
    for (int fm = 0; fm < 4; fm++) {
        aHi[fm][0] = *(const half8*)(Ab + rA + (4 + fm) * 1024 + cbo0);
        aHi[fm][1] = *(const half8*)(Ab + rA + (4 + fm) * 1024 + cbo1);
    }
    asm volatile("s_waitcnt lgkmcnt(8)" ::: "memory"); SB0;
    PRIO1;
#pragma unroll
    for (int fm = 0; fm < 4; fm++)
#pragma unroll
        for (int fn = 0; fn < 2; fn++) {
            acc[fm][2 + fn] = MF(aLo[fm][0], bHi[fn][0], acc[fm][2 + fn]);
            acc[fm][2 + fn] = MF(aLo[fm][1], bHi[fn][1], acc[fm][2 + fn]);
        }
    PRIO0;

    // ---- ph2 ----
    asm volatile("s_waitcnt lgkmcnt(0)" ::: "memory"); SB0;
    PRIO1;
#pragma unroll
    for (int fm = 0; fm < 4; fm++)
#pragma unroll
        for (int fn = 0; fn < 2; fn++) {
            acc[4 + fm][fn] = MF(aHi[fm][0], bLo[fn][0], acc[4 + fm][fn]);
            acc[4 + fm][fn] = MF(aHi[fm][1], bLo[fn][1], acc[4 + fm][fn]);
        }
    PRIO0;
    if constexpr (MODE != 2) {
        BARR;  // consumed: all waves' buf-t reads retired
        if constexpr (MODE == 0) {
            _Float16* Ad = As + bufR * 16384;
            _Float16* Bd = Bs + bufR * 16384;
            gload_lds16(aS0 + (size_t)kt2 * 64, Ad + ldA);
            gload_lds16(aS1 + (size_t)kt2 * 64, Ad + 4096 + ldA);
            gload_lds16(aS2 + (size_t)kt2 * 64, Ad + 8192 + ldA);
            gload_lds16(aS3 + (size_t)kt2 * 64, Ad + 12288 + ldA);
            gload_lds16(bS0 + (size_t)kt2 * 64, Bd + sdB);
            gload_lds16(bS1 + (size_t)kt2 * 64, Bd + 2048 + sdB);
            gload_lds16(bS2 + (size_t)kt2 * 64, Bd + 8192 + sdB);
            gload_lds16(bS3 + (size_t)kt2 * 64, Bd + 10240 + sdB);
            asm volatile("s_waitcnt vmcnt(8)" ::: "memory");
        } else {
            asm volatile("s_waitcnt vmcnt(0)" ::: "memory");
        }
        BARR;  // buf t+1 ready
    }

    // ---- ph3 ----
    if constexpr (MODE != 2) {
#pragma unroll
        for (int fm = 0; fm < 4; fm++) {
            aLo[fm][0] = *(const half8*)(AbN + rA + fm * 1024 + cbo0);
            aLo[fm][1] = *(const half8*)(AbN + rA + fm * 1024 + cbo1);
        }
#pragma unroll
        for (int fn = 0; fn < 2; fn++) {
            bLo[fn][0] = *(const half8*)(BbN + rB + fn * 1024 + cbo0);
            bLo[fn][1] = *(const half8*)(BbN + rB + fn * 1024 + cbo1);
        }
    }
    PRIO1;
#pragma unroll
    for (int fm = 0; fm < 4; fm++)
#pragma unroll
        for (int fn = 0; fn < 2; fn++) {
            acc[4 + fm][2 + fn] = MF(aHi[fm][0], bHi[fn][0], acc[4 + fm][2 + fn]);
            acc[4 + fm][2 + fn] = MF(aHi[fm][1], bHi[fn][1], acc[4 + fm][2 + fn]);
        }
    PRIO0;
}

template<int LAYER>
__global__ __launch_bounds__(512, 2) void k_gemm(const _Float16* __restrict__ Ain,
                                                 const _Float16* __restrict__ Bt,
                                                 const float* __restrict__ bias,
                                                 const int* __restrict__ counts,
                                                 const int* __restrict__ offs,
                                                 const int* __restrict__ ltok,
                                                 const float* __restrict__ lw,
                                                 _Float16* __restrict__ Cout) {
    __shared__ _Float16 As[2 * 256 * 64];
    __shared__ _Float16 Bs[2 * 256 * 64];

    // XCD-expert affinity: xs=(x&7)*8+(x>>3); XCD c owns expert c's B panel.
    int xs = (blockIdx.x & 7) * 8 + (blockIdx.x >> 3);
    int e  = xs >> 3;
    int n0 = (xs & 7) * 256;
    int cnt = counts[e];
    int m0 = blockIdx.y * 256;
    if (m0 >= cnt) return;
    int base = offs[e];

    int tid = threadIdx.x;
    int l = tid & 63;
    int wid = tid >> 6;
    int wm = wid >> 2, wn = wid & 3;
    int lr = l & 15, lk = l >> 4;
    int cbo0 = ((lk) ^ (lr & 7)) * 8;
    int cbo1 = ((4 + lk) ^ (lr & 7)) * 8;
    int rA = (wm * 128 + lr) * 64;
    int rB = (wn * 64 + lr) * 64;

    // staging geometry (lane-linear 16B dest within each wave - m104-safe)
    int srowA = tid >> 3;                 // 0..63
    int ldA   = tid * 8;                  // A dest (halves)
    int srowB = ((wid & 3) * 8) + ((wid >> 2) * 64) + ((l >> 3)); // B row
    int sdB   = srowB * 64 + (l & 7) * 8; // B dest (halves)
    size_t koff = (size_t)(((tid & 7) ^ ((tid >> 3) & 7)) * 8);   // pre-swizzled

    const _Float16* aS[4];
#pragma unroll
    for (int j = 0; j < 4; j++) {
        int r = m0 + srowA + j * 64; if (r > cnt - 1) r = cnt - 1;
        if constexpr (LAYER == 1) {
            int tok = ltok[base + r];
            aS[j] = Ain + (size_t)tok * DIM + koff;
        } else {
            aS[j] = Ain + (size_t)(base + r) * HID + koff;
        }
    }
    const int brow[4] = {0, 32, 128, 160};
    const _Float16* bS[4];
#pragma unroll
    for (int j = 0; j < 4; j++)
        bS[j] = Bt + ((size_t)(e * 2048 + n0 + srowB + brow[j])) * 2048 + koff;

    floatx4 acc[8][4];
#pragma unroll
    for (int m = 0; m < 8; m++)
#pragma unroll
        for (int n = 0; n < 4; n++) acc[m][n] = (floatx4){0.f, 0.f, 0.f, 0.f};

    // prologue: stage tile0 -> buf0, tile1 -> buf1; vmcnt(8): tile0 landed.
#pragma unroll
    for (int T = 0; T < 2; T++) {
        _Float16* Ad = As + T * 16384;
        _Float16* Bd = Bs + T * 16384;
        gload_lds16(aS[0] + (size_t)T * 64, Ad + ldA);
        gload_lds16(aS[1] + (size_t)T * 64, Ad + 4096 + ldA);
        gload_lds16(aS[2] + (size_t)T * 64, Ad + 8192 + ldA);
        gload_lds16(aS[3] + (size_t)T * 64, Ad + 12288 + ldA);
        gload_lds16(bS[0] + (size_t)T * 64, Bd + sdB);
        gload_lds16(bS[1] + (size_t)T * 64, Bd + 2048 + sdB);
        gload_lds16(bS[2] + (size_t)T * 64, Bd + 8192 + sdB);
        gload_lds16(bS[3] + (size_t)T * 64, Bd + 10240 + sdB);
    }
    asm volatile("s_waitcnt vmcnt(8)" ::: "memory");
    BARR;

    half8 aLo[4][2], aHi[4][2], bLo[2][2], bHi[2][2];
    // pre-read tile0's aLo,bLo (retired by ph0's lgkmcnt(4))
#pragma unroll
    for (int fm = 0; fm < 4; fm++) {
        aLo[fm][0] = *(const half8*)(As + rA + fm * 1024 + cbo0);
        aLo[fm][1] = *(const half8*)(As + rA + fm * 1024 + cbo1);
    }
#pragma unroll
    for (int fn = 0; fn < 2; fn++) {
        bLo[fn][0] = *(const half8*)(Bs + rB + fn * 1024 + cbo0);
        bLo[fn][1] = *(const half8*)(Bs + rB + fn * 1024 + cbo1);
    }

#pragma unroll 1
    for (int t = 0; t < 30; ++t)
        tileQ<0>(As, Bs, t & 1, t + 2, aS[0], aS[1], aS[2], aS[3],
                 bS[0], bS[1], bS[2], bS[3], ldA, sdB, rA, rB, cbo0, cbo1,
                 aLo, aHi, bLo, bHi, acc);
    tileQ<1>(As, Bs, 0, 0, aS[0], aS[1], aS[2], aS[3],
             bS[0], bS[1], bS[2], bS[3], ldA, sdB, rA, rB, cbo0, cbo1,
             aLo, aHi, bLo, bHi, acc);
    tileQ<2>(As, Bs, 1, 0, aS[0], aS[1], aS[2], aS[3],
             bS[0], bS[1], bS[2], bS[3], ldA, sdB, rA, rB, cbo0, cbo1,
             aLo, aHi, bLo, bHi, acc);

    // epilogue
#pragma unroll
    for (int fm = 0; fm < 8; fm++) {
        int row0 = m0 + wm * 128 + fm * 16 + lk * 4;
#pragma unroll
        for (int fn = 0; fn < 4; fn++) {
            int col = n0 + wn * 64 + fn * 16 + lr;
            float bv = bias[e * 2048 + col];
#pragma unroll
            for (int r = 0; r < 4; r++) {
                int row = row0 + r;
                if (row < cnt) {
                    float v = acc[fm][fn][r] + bv;
                    if constexpr (LAYER == 1) {
                        v = v > 0.f ? v : 0.f;
                    } else {
                        v *= lw[base + row];
                    }
                    Cout[(size_t)(base + row) * HID + col] = (_Float16)v;
                }
            }
        }
    }
}

// ---------------- combine the two weighted expert rows per token ----------------
__global__ __launch_bounds__(256) void k_combine(const _Float16* __restrict__ yb,
                                                 const int* __restrict__ tslot,
                                                 float* __restrict__ out) {
    int t = blockIdx.x;
    int s0 = tslot[2 * t], s1 = tslot[2 * t + 1];
    int c = threadIdx.x * 8;
    half8 y0 = *(const half8*)&yb[(size_t)s0 * HID + c];
    half8 y1 = *(const half8*)&yb[(size_t)s1 * HID + c];
    float* op = out + (size_t)t * HID + c;
    float4 o;
    o.x = (float)y0[0] + (float)y1[0];
    o.y = (float)y0[1] + (float)y1[1];
    o.z = (float)y0[2] + (float)y1[2];
    o.w = (float)y0[3] + (float)y1[3];
    *(float4*)(op) = o;
    o.x = (float)y0[4] + (float)y1[4];
    o.y = (float)y0[5] + (float)y1[5];
    o.z = (float)y0[6] + (float)y1[6];
    o.w = (float)y0[7] + (float)y1[7];
    *(float4*)(op + 4) = o;
}

extern "C" void kernel_launch(void* const* d_in, const int* in_sizes, int n_in,
                              void* d_out, int out_size, void* d_ws, size_t ws_size,
                              hipStream_t stream) {
    const float* x  = (const float*)d_in[0];
    const float* Wg = (const float*)d_in[1];
    const float* bg = (const float*)d_in[2];
    const float* W1 = (const float*)d_in[3];
    const float* b1 = (const float*)d_in[4];
    const float* W2 = (const float*)d_in[5];
    const float* b2 = (const float*)d_in[6];
    float* out = (float*)d_out;

    char* ws = (char*)d_ws;
    _Float16* xh  = (_Float16*)(ws);                       // 33,554,432 B
    _Float16* w1t = (_Float16*)(ws + 33554432ULL);         // 67,108,864 B
    _Float16* w2t = (_Float16*)(ws + 100663296ULL);        // 67,108,864 B
    _Float16* hb  = (_Float16*)(ws + 167772160ULL);        // 67,108,864 B
    _Float16* yb  = (_Float16*)(ws + 234881024ULL);        // 67,108,864 B
    char* rt = ws + 301989888ULL;
    int*   counts = (int*)(rt);             // 8 ints
    int*   fill   = (int*)(rt + 32);        // 8 ints
    int*   offs   = (int*)(rt + 64);        // 9 ints
    int*   te     = (int*)(rt + 128);
    float* tw     = (float*)(rt + 128 + 65536);
    int*   ltok   = (int*)(rt + 128 + 131072);
    float* lw     = (float*)(rt + 128 + 196608);
    int*   tslot  = (int*)(rt + 128 + 262144);

    hipMemsetAsync(rt, 0, 64, stream);  // counts + fill
    k_prep<<<dim3(32, 32, 16), 256, 0, stream>>>(W1, W2, w1t, w2t);
    k_gate<<<512, 256, 0, stream>>>(x, Wg, bg, xh, te, tw, counts);
    k_scan<<<1, 64, 0, stream>>>(counts, offs, fill);
    k_scatter<<<32, 256, 0, stream>>>(te, tw, offs, fill, ltok, lw, tslot);
    k_gemm<1><<<dim3(64, 32), 512, 0, stream>>>(xh, w1t, b1, counts, offs, ltok, nullptr, hb);
    k_gemm<2><<<dim3(64, 32), 512, 0, stream>>>(hb, w2t, b2, counts, offs, ltok, lw, yb);
    k_combine<<<8192, 256, 0, stream>>>(yb, tslot, out);
}

// Round 9
// 616.626 us; speedup vs baseline: 1.0968x; 1.0968x over previous
//
#include <hip/hip_runtime.h>
#include <hip/hip_bf16.h>
#include <cstdint>
#include <cstddef>

#define N_TOK 8192
#define DIM   2048
#define HID   2048
#define NE    8

typedef _Float16 half8  __attribute__((ext_vector_type(8)));
typedef _Float16 half4v __attribute__((ext_vector_type(4)));
typedef float    floatx4 __attribute__((ext_vector_type(4)));

#define BARR  __builtin_amdgcn_s_barrier()
#define SB0   __builtin_amdgcn_sched_barrier(0)
#define PRIO1 __builtin_amdgcn_s_setprio(1)
#define PRIO0 __builtin_amdgcn_s_setprio(0)
#define LGKM0 asm volatile("s_waitcnt lgkmcnt(0)" ::: "memory")
#define LGKM8 asm volatile("s_waitcnt lgkmcnt(8)" ::: "memory")

__device__ inline void gload_lds16(const void* g, void* l) {
    __builtin_amdgcn_global_load_lds(
        (const __attribute__((address_space(1))) unsigned int*)g,
        (__attribute__((address_space(3))) unsigned int*)l, 16, 0, 0);
}

__device__ __forceinline__ floatx4 MF(half8 a, half8 b, floatx4 c) {
    return __builtin_amdgcn_mfma_f32_16x16x32_f16(a, b, c, 0, 0, 0);
}

// ---------------- fused W1+W2 [E][R][C] fp32 -> [E][C][R] fp16 ----------------
__global__ __launch_bounds__(256) void k_prep(const float* __restrict__ W1,
                                              const float* __restrict__ W2,
                                              _Float16* __restrict__ w1t,
                                              _Float16* __restrict__ w2t) {
    __shared__ float tile[64][65];
    int z = blockIdx.z;
    const float* in = (z < 8) ? W1 : W2;
    _Float16* out   = (z < 8) ? w1t : w2t;
    int e  = z & 7;
    int r0 = blockIdx.y * 64;
    int c0 = blockIdx.x * 64;
    int tc = threadIdx.x & 63, tr = threadIdx.x >> 6;
    const float* ip = in + ((size_t)e * 2048 + r0) * 2048 + c0;
#pragma unroll
    for (int i = 0; i < 16; i++)
        tile[tr + i * 4][tc] = ip[(size_t)(tr + i * 4) * 2048 + tc];
    __syncthreads();
    _Float16* op = out + ((size_t)e * 2048 + c0) * 2048 + r0;
#pragma unroll
    for (int i = 0; i < 16; i++) {
        int cc = tr + i * 4;
        op[(size_t)cc * 2048 + tc] = (_Float16)tile[tc][cc];
    }
}

// ---------------- gate: fp64-accum logits, top-2, softmax; fuses x->fp16 ----------------
__global__ __launch_bounds__(256) void k_gate(const float* __restrict__ x,
                                              const float* __restrict__ Wg,
                                              const float* __restrict__ bg,
                                              _Float16* __restrict__ xh,
                                              int* __restrict__ te, float* __restrict__ tw,
                                              int* __restrict__ counts) {
    __shared__ float wgs[NE * DIM]; // 64 KB, transposed [e][d]
    __shared__ int lcnt[NE];
    if (threadIdx.x < NE) lcnt[threadIdx.x] = 0;
    for (int i = threadIdx.x; i < NE * DIM; i += 256)
        wgs[(i & 7) * DIM + (i >> 3)] = Wg[i];
    __syncthreads();
    int wv = threadIdx.x >> 6, l = threadIdx.x & 63;
#pragma unroll 1
    for (int it = 0; it < 4; ++it) {
        int t = blockIdx.x * 16 + wv * 4 + it;
        const float* xr = x + (size_t)t * DIM;
        double acc[NE] = {0, 0, 0, 0, 0, 0, 0, 0};
#pragma unroll 2
        for (int i = 0; i < 8; i++) {
            int d0 = i * 256 + l * 4;
            float4 xv = *(const float4*)(xr + d0);
            half4v hv;
            hv[0] = (_Float16)xv.x; hv[1] = (_Float16)xv.y;
            hv[2] = (_Float16)xv.z; hv[3] = (_Float16)xv.w;
            *(half4v*)(xh + (size_t)t * DIM + d0) = hv;
#pragma unroll
            for (int e = 0; e < NE; e++) {
                float4 w4 = *(const float4*)(wgs + e * DIM + d0);
                acc[e] += (double)xv.x * w4.x + (double)xv.y * w4.y +
                          (double)xv.z * w4.z + (double)xv.w * w4.w;
            }
        }
#pragma unroll
        for (int e = 0; e < NE; e++) {
            double v = acc[e];
            v += __shfl_xor(v, 32, 64); v += __shfl_xor(v, 16, 64);
            v += __shfl_xor(v, 8, 64);  v += __shfl_xor(v, 4, 64);
            v += __shfl_xor(v, 2, 64);  v += __shfl_xor(v, 1, 64);
            acc[e] = v;
        }
        if (l == 0) {
            double best0 = -1e300, best1 = -1e300; int i0 = 0, i1 = 0;
#pragma unroll
            for (int e = 0; e < NE; e++) {
                double lg = acc[e] + (double)bg[e];
                if (lg > best0) { best1 = best0; i1 = i0; best0 = lg; i0 = e; }
                else if (lg > best1) { best1 = lg; i1 = e; }
            }
            float d  = expf((float)(best1 - best0));
            float w0 = 1.f / (1.f + d), w1 = d / (1.f + d);
            te[2 * t] = i0; te[2 * t + 1] = i1;
            tw[2 * t] = w0; tw[2 * t + 1] = w1;
            atomicAdd(&lcnt[i0], 1);
            atomicAdd(&lcnt[i1], 1);
        }
    }
    __syncthreads();
    if (threadIdx.x < NE) atomicAdd(&counts[threadIdx.x], lcnt[threadIdx.x]);
}

// ---------------- tiny scan ----------------
__global__ void k_scan(const int* __restrict__ counts, int* __restrict__ offs,
                       int* __restrict__ fill) {
    if (threadIdx.x == 0 && blockIdx.x == 0) {
        int s = 0;
        for (int e = 0; e < NE; e++) { offs[e] = s; s += counts[e]; fill[e] = 0; }
        offs[NE] = s;
    }
}

// ---------------- scatter tokens to expert lists ----------------
__global__ __launch_bounds__(256) void k_scatter(const int* __restrict__ te,
                                                 const float* __restrict__ tw,
                                                 const int* __restrict__ offs,
                                                 int* __restrict__ fill,
                                                 int* __restrict__ ltok,
                                                 float* __restrict__ lw,
                                                 int* __restrict__ tslot) {
    int t = blockIdx.x * blockDim.x + threadIdx.x;
    if (t >= N_TOK) return;
#pragma unroll
    for (int k = 0; k < 2; k++) {
        int e = te[2 * t + k];
        int p = atomicAdd(&fill[e], 1);
        int idx = offs[e] + p;
        ltok[idx] = t; lw[idx] = tw[2 * t + k]; tslot[2 * t + k] = idx;
    }
}

// ============ 8-phase m201-template GEMM: BM=BN=256, BK=64, 2 K-tiles/iter ============
// 512 thr = 8 waves (2m x 4n); wave tile 128x64; acc[8][4] of 16x16x32_f16.
// LDS: A[2][256][64] + B[2][256][64] fp16 = 128 KB.  Tile t -> buf t&1.
// Region free-times (per-phase end barriers): within an iteration consuming
// T0=buf0 (P1-P4) and T1=buf1 (P5-P8):
//   Alo/Ahi(buf0) read P1+P3 -> free >=P4;  Blo/Bhi(buf0) read P1+P2 -> free >=P3
//   Alo/Ahi(buf1) read P5+P7 -> free >=P8;  Blo/Bhi(buf1) read P5+P6 -> free >=P7
// Stage slots (half-tile = 2 gloads/thread):
//   P3: Blo(t+2)  P4: Alo(t+2)  P5: Bhi(t+2)+Ahi(t+2)  P7: Blo(t+3)
//   P8: Bhi(t+3)+Alo(t+3)+Ahi(t+3)
// Checkpoints (per-thread ledger, steady state):
//   P4: outstanding = prevP7(2)+prevP8(6)+P3(2)+P4(2)=12 -> vmcnt(4) forces
//       oldest 8 = ALL of tile t+1 (consumed P5-P8); youngest forced is 4
//       phases (~1200cyc) old -> no latency stall.
//   P8: outstanding = P3(2)+P4(2)+P5(4)+P7(2)+P8(6)=16 -> vmcnt(8) forces
//       P3..P5 = ALL of tile t+2 (consumed next P1-P4); youngest 3 phases old.
// XOR swizzle both-sides (rule 21): physical 16B chunk = logical ^ (row&7).

template<int MODE>  // 0: steady (stage t+2,t+3); 1: final iter (no stage)
__device__ __forceinline__ void iter8(
    _Float16* As, _Float16* Bs, int t2,
    const _Float16* aS0, const _Float16* aS1, const _Float16* aS2, const _Float16* aS3,
    const _Float16* bS0, const _Float16* bS1, const _Float16* bS2, const _Float16* bS3,
    int sd, int rA, int rB, int cbo0, int cbo1,
    floatx4 (&acc)[8][4])
{
    const int t3 = t2 + 1;
    const _Float16* Ab0 = As;
    const _Float16* Bb0 = Bs;
    const _Float16* Ab1 = As + 16384;
    const _Float16* Bb1 = Bs + 16384;
    half8 aF[4][2], bA[2][2], bB[2][2];

    // ---------- P1: 12 reads (a fm0-3 + b fn0-1, buf0); MFMA Q00 ----------
#pragma unroll
    for (int fm = 0; fm < 4; fm++) {
        aF[fm][0] = *(const half8*)(Ab0 + rA + fm * 1024 + cbo0);
        aF[fm][1] = *(const half8*)(Ab0 + rA + fm * 1024 + cbo1);
    }
#pragma unroll
    for (int fn = 0; fn < 2; fn++) {
        bA[fn][0] = *(const half8*)(Bb0 + rB + fn * 1024 + cbo0);
        bA[fn][1] = *(const half8*)(Bb0 + rB + fn * 1024 + cbo1);
    }
    LGKM8;
    BARR; LGKM0; SB0;
    PRIO1;
#pragma unroll
    for (int fm = 0; fm < 4; fm++)
#pragma unroll
        for (int fn = 0; fn < 2; fn++) {
            acc[fm][fn] = MF(aF[fm][0], bA[fn][0], acc[fm][fn]);
            acc[fm][fn] = MF(aF[fm][1], bA[fn][1], acc[fm][fn]);
        }
    PRIO0;
    BARR;

    // ---------- P2: 4 reads (b fn2-3, buf0); MFMA Q01 ----------
#pragma unroll
    for (int fn = 0; fn < 2; fn++) {
        bB[fn][0] = *(const half8*)(Bb0 + rB + (2 + fn) * 1024 + cbo0);
        bB[fn][1] = *(const half8*)(Bb0 + rB + (2 + fn) * 1024 + cbo1);
    }
    BARR; LGKM0; SB0;
    PRIO1;
#pragma unroll
    for (int fm = 0; fm < 4; fm++)
#pragma unroll
        for (int fn = 0; fn < 2; fn++) {
            acc[fm][2 + fn] = MF(aF[fm][0], bB[fn][0], acc[fm][2 + fn]);
            acc[fm][2 + fn] = MF(aF[fm][1], bB[fn][1], acc[fm][2 + fn]);
        }
    PRIO0;
    BARR;

    // ---------- P3: 8 reads (a fm4-7, buf0); stage Blo(t+2); MFMA Q10 ----------
#pragma unroll
    for (int fm = 0; fm < 4; fm++) {
        aF[fm][0] = *(const half8*)(Ab0 + rA + (4 + fm) * 1024 + cbo0);
        aF[fm][1] = *(const half8*)(Ab0 + rA + (4 + fm) * 1024 + cbo1);
    }
    if constexpr (MODE == 0) {
        gload_lds16(bS0 + (size_t)t2 * 64, Bs + sd);
        gload_lds16(bS1 + (size_t)t2 * 64, Bs + 4096 + sd);
    }
    BARR; LGKM0; SB0;
    PRIO1;
#pragma unroll
    for (int fm = 0; fm < 4; fm++)
#pragma unroll
        for (int fn = 0; fn < 2; fn++) {
            acc[4 + fm][fn] = MF(aF[fm][0], bA[fn][0], acc[4 + fm][fn]);
            acc[4 + fm][fn] = MF(aF[fm][1], bA[fn][1], acc[4 + fm][fn]);
        }
    PRIO0;
    BARR;

    // ---------- P4: stage Alo(t+2); MFMA Q11; vmcnt(4) ----------
    if constexpr (MODE == 0) {
        gload_lds16(aS0 + (size_t)t2 * 64, As + sd);
        gload_lds16(aS1 + (size_t)t2 * 64, As + 4096 + sd);
    }
    BARR; LGKM0; SB0;
    PRIO1;
#pragma unroll
    for (int fm = 0; fm < 4; fm++)
#pragma unroll
        for (int fn = 0; fn < 2; fn++) {
            acc[4 + fm][2 + fn] = MF(aF[fm][0], bB[fn][0], acc[4 + fm][2 + fn]);
            acc[4 + fm][2 + fn] = MF(aF[fm][1], bB[fn][1], acc[4 + fm][2 + fn]);
        }
    PRIO0;
    if constexpr (MODE == 0) asm volatile("s_waitcnt vmcnt(4)" ::: "memory");
    else                     asm volatile("s_waitcnt vmcnt(0)" ::: "memory");
    BARR;

    // ---------- P5: 12 reads (buf1); stage Bhi(t+2)+Ahi(t+2); MFMA Q00 ----------
#pragma unroll
    for (int fm = 0; fm < 4; fm++) {
        aF[fm][0] = *(const half8*)(Ab1 + rA + fm * 1024 + cbo0);
        aF[fm][1] = *(const half8*)(Ab1 + rA + fm * 1024 + cbo1);
    }
#pragma unroll
    for (int fn = 0; fn < 2; fn++) {
        bA[fn][0] = *(const half8*)(Bb1 + rB + fn * 1024 + cbo0);
        bA[fn][1] = *(const half8*)(Bb1 + rB + fn * 1024 + cbo1);
    }
    if constexpr (MODE == 0) {
        gload_lds16(bS2 + (size_t)t2 * 64, Bs + 8192 + sd);
        gload_lds16(bS3 + (size_t)t2 * 64, Bs + 12288 + sd);
        gload_lds16(aS2 + (size_t)t2 * 64, As + 8192 + sd);
        gload_lds16(aS3 + (size_t)t2 * 64, As + 12288 + sd);
    }
    LGKM8;
    BARR; LGKM0; SB0;
    PRIO1;
#pragma unroll
    for (int fm = 0; fm < 4; fm++)
#pragma unroll
        for (int fn = 0; fn < 2; fn++) {
            acc[fm][fn] = MF(aF[fm][0], bA[fn][0], acc[fm][fn]);
            acc[fm][fn] = MF(aF[fm][1], bA[fn][1], acc[fm][fn]);
        }
    PRIO0;
    BARR;

    // ---------- P6: 4 reads (b fn2-3, buf1); MFMA Q01 ----------
#pragma unroll
    for (int fn = 0; fn < 2; fn++) {
        bB[fn][0] = *(const half8*)(Bb1 + rB + (2 + fn) * 1024 + cbo0);
        bB[fn][1] = *(const half8*)(Bb1 + rB + (2 + fn) * 1024 + cbo1);
    }
    BARR; LGKM0; SB0;
    PRIO1;
#pragma unroll
    for (int fm = 0; fm < 4; fm++)
#pragma unroll
        for (int fn = 0; fn < 2; fn++) {
            acc[fm][2 + fn] = MF(aF[fm][0], bB[fn][0], acc[fm][2 + fn]);
            acc[fm][2 + fn] = MF(aF[fm][1], bB[fn][1], acc[fm][2 + fn]);
        }
    PRIO0;
    BARR;

    // ---------- P7: 8 reads (a fm4-7, buf1); stage Blo(t+3); MFMA Q10 ----------
#pragma unroll
    for (int fm = 0; fm < 4; fm++) {
        aF[fm][0] = *(const half8*)(Ab1 + rA + (4 + fm) * 1024 + cbo0);
        aF[fm][1] = *(const half8*)(Ab1 + rA + (4 + fm) * 1024 + cbo1);
    }
    if constexpr (MODE == 0) {
        gload_lds16(bS0 + (size_t)t3 * 64, Bs + 16384 + sd);
        gload_lds16(bS1 + (size_t)t3 * 64, Bs + 16384 + 4096 + sd);
    }
    BARR; LGKM0; SB0;
    PRIO1;
#pragma unroll
    for (int fm = 0; fm < 4; fm++)
#pragma unroll
        for (int fn = 0; fn < 2; fn++) {
            acc[4 + fm][fn] = MF(aF[fm][0], bA[fn][0], acc[4 + fm][fn]);
            acc[4 + fm][fn] = MF(aF[fm][1], bA[fn][1], acc[4 + fm][fn]);
        }
    PRIO0;
    BARR;

    // ---------- P8: stage Bhi+Alo+Ahi(t+3); MFMA Q11; vmcnt(8) ----------
    if constexpr (MODE == 0) {
        gload_lds16(bS2 + (size_t)t3 * 64, Bs + 16384 + 8192 + sd);
        gload_lds16(bS3 + (size_t)t3 * 64, Bs + 16384 + 12288 + sd);
        gload_lds16(aS0 + (size_t)t3 * 64, As + 16384 + sd);
        gload_lds16(aS1 + (size_t)t3 * 64, As + 16384 + 4096 + sd);
        gload_lds16(aS2 + (size_t)t3 * 64, As + 16384 + 8192 + sd);
        gload_lds16(aS3 + (size_t)t3 * 64, As + 16384 + 12288 + sd);
    }
    BARR; LGKM0; SB0;
    PRIO1;
#pragma unroll
    for (int fm = 0; fm < 4; fm++)
#pragma unroll
        for (int fn = 0; fn < 2; fn++) {
            acc[4 + fm][2 + fn] = MF(aF[fm][0], bB[fn][0], acc[4 + fm][2 + fn]);
            acc[4 + fm][2 + fn] = MF(aF[fm][1], bB[fn][1], acc[4 + fm][2 + fn]);
        }
    PRIO0;
    if constexpr (MODE == 0) asm volatile("s_waitcnt vmcnt(8)" ::: "memory");
    BARR;
}

template<int LAYER>
__global__ __launch_bounds__(512, 2) void k_gemm(const _Float16* __restrict__ Ain,
                                                 const _Float16* __restrict__ Bt,
                                                 const float* __restrict__ bias,
                                                 const int* __restrict__ counts,
                                                 const int* __restrict__ offs,
                                                 const int* __restrict__ ltok,
                                                 const float* __restrict__ lw,
                                                 _Float16* __restrict__ Cout) {
    __shared__ _Float16 As[2 * 256 * 64];
    __shared__ _Float16 Bs[2 * 256 * 64];

    // XCD-expert affinity: xs=(x&7)*8+(x>>3); XCD c owns expert c's B panel.
    int xs = (blockIdx.x & 7) * 8 + (blockIdx.x >> 3);
    int e  = xs >> 3;
    int n0 = (xs & 7) * 256;
    int cnt = counts[e];
    int m0 = blockIdx.y * 256;
    if (m0 >= cnt) return;
    int base = offs[e];

    int tid = threadIdx.x;
    int l = tid & 63;
    int wid = tid >> 6;
    int wm = wid >> 2, wn = wid & 3;
    int lr = l & 15, lk = l >> 4;
    int cbo0 = ((lk) ^ (lr & 7)) * 8;
    int cbo1 = ((4 + lk) ^ (lr & 7)) * 8;
    int rA = (wm * 128 + lr) * 64;
    int rB = (wn * 64 + lr) * 64;

    // staging geometry: thread covers row (tid>>3)+j*64 (j=0,1 per half),
    // physical chunk tid&7; dest lane-linear (wave base + lane*16B, m104-safe).
    int sd = (tid >> 3) * 64 + (tid & 7) * 8;
    size_t koff = (size_t)(((tid & 7) ^ ((tid >> 3) & 7)) * 8);   // pre-swizzled

    const _Float16* aS[4];
#pragma unroll
    for (int j = 0; j < 4; j++) {
        int r = m0 + (tid >> 3) + j * 64; if (r > cnt - 1) r = cnt - 1;
        if constexpr (LAYER == 1) {
            int tok = ltok[base + r];
            aS[j] = Ain + (size_t)tok * DIM + koff;
        } else {
            aS[j] = Ain + (size_t)(base + r) * HID + koff;
        }
    }
    const _Float16* bS[4];
#pragma unroll
    for (int j = 0; j < 4; j++)
        bS[j] = Bt + ((size_t)(e * 2048 + n0 + (tid >> 3) + j * 64)) * 2048 + koff;

    floatx4 acc[8][4];
#pragma unroll
    for (int m = 0; m < 8; m++)
#pragma unroll
        for (int n = 0; n < 4; n++) acc[m][n] = (floatx4){0.f, 0.f, 0.f, 0.f};

    // prologue: stage tile0 -> buf0 (8 loads), tile1 -> buf1 (8); vmcnt(8): tile0 in.
#pragma unroll
    for (int T = 0; T < 2; T++) {
        _Float16* Ad = As + T * 16384;
        _Float16* Bd = Bs + T * 16384;
        gload_lds16(aS[0] + (size_t)T * 64, Ad + sd);
        gload_lds16(aS[1] + (size_t)T * 64, Ad + 4096 + sd);
        gload_lds16(aS[2] + (size_t)T * 64, Ad + 8192 + sd);
        gload_lds16(aS[3] + (size_t)T * 64, Ad + 12288 + sd);
        gload_lds16(bS[0] + (size_t)T * 64, Bd + sd);
        gload_lds16(bS[1] + (size_t)T * 64, Bd + 4096 + sd);
        gload_lds16(bS[2] + (size_t)T * 64, Bd + 8192 + sd);
        gload_lds16(bS[3] + (size_t)T * 64, Bd + 12288 + sd);
    }
    asm volatile("s_waitcnt vmcnt(8)" ::: "memory");
    BARR;

#pragma unroll 1
    for (int i = 0; i < 15; ++i)
        iter8<0>(As, Bs, 2 * i + 2, aS[0], aS[1], aS[2], aS[3],
                 bS[0], bS[1], bS[2], bS[3], sd, rA, rB, cbo0, cbo1, acc);
    iter8<1>(As, Bs, 0, aS[0], aS[1], aS[2], aS[3],
             bS[0], bS[1], bS[2], bS[3], sd, rA, rB, cbo0, cbo1, acc);

    // epilogue
#pragma unroll
    for (int fm = 0; fm < 8; fm++) {
        int row0 = m0 + wm * 128 + fm * 16 + lk * 4;
#pragma unroll
        for (int fn = 0; fn < 4; fn++) {
            int col = n0 + wn * 64 + fn * 16 + lr;
            float bv = bias[e * 2048 + col];
#pragma unroll
            for (int r = 0; r < 4; r++) {
                int row = row0 + r;
                if (row < cnt) {
                    float v = acc[fm][fn][r] + bv;
                    if constexpr (LAYER == 1) {
                        v = v > 0.f ? v : 0.f;
                    } else {
                        v *= lw[base + row];
                    }
                    Cout[(size_t)(base + row) * HID + col] = (_Float16)v;
                }
            }
        }
    }
}

// ---------------- combine the two weighted expert rows per token ----------------
__global__ __launch_bounds__(256) void k_combine(const _Float16* __restrict__ yb,
                                                 const int* __restrict__ tslot,
                                                 float* __restrict__ out) {
    int t = blockIdx.x;
    int s0 = tslot[2 * t], s1 = tslot[2 * t + 1];
    int c = threadIdx.x * 8;
    half8 y0 = *(const half8*)&yb[(size_t)s0 * HID + c];
    half8 y1 = *(const half8*)&yb[(size_t)s1 * HID + c];
    float* op = out + (size_t)t * HID + c;
    float4 o;
    o.x = (float)y0[0] + (float)y1[0];
    o.y = (float)y0[1] + (float)y1[1];
    o.z = (float)y0[2] + (float)y1[2];
    o.w = (float)y0[3] + (float)y1[3];
    *(float4*)(op) = o;
    o.x = (float)y0[4] + (float)y1[4];
    o.y = (float)y0[5] + (float)y1[5];
    o.z = (float)y0[6] + (float)y1[6];
    o.w = (float)y0[7] + (float)y1[7];
    *(float4*)(op + 4) = o;
}

extern "C" void kernel_launch(void* const* d_in, const int* in_sizes, int n_in,
                              void* d_out, int out_size, void* d_ws, size_t ws_size,
                              hipStream_t stream) {
    const float* x  = (const float*)d_in[0];
    const float* Wg = (const float*)d_in[1];
    const float* bg = (const float*)d_in[2];
    const float* W1 = (const float*)d_in[3];
    const float* b1 = (const float*)d_in[4];
    const float* W2 = (const float*)d_in[5];
    const float* b2 = (const float*)d_in[6];
    float* out = (float*)d_out;

    char* ws = (char*)d_ws;
    _Float16* xh  = (_Float16*)(ws);                       // 33,554,432 B
    _Float16* w1t = (_Float16*)(ws + 33554432ULL);         // 67,108,864 B
    _Float16* w2t = (_Float16*)(ws + 100663296ULL);        // 67,108,864 B
    _Float16* hb  = (_Float16*)(ws + 167772160ULL);        // 67,108,864 B
    _Float16* yb  = (_Float16*)(ws + 234881024ULL);        // 67,108,864 B
    char* rt = ws + 301989888ULL;
    int*   counts = (int*)(rt);             // 8 ints
    int*   fill   = (int*)(rt + 32);        // 8 ints
    int*   offs   = (int*)(rt + 64);        // 9 ints
    int*   te     = (int*)(rt + 128);
    float* tw     = (float*)(rt + 128 + 65536);
    int*   ltok   = (int*)(rt + 128 + 131072);
    float* lw     = (float*)(rt + 128 + 196608);
    int*   tslot  = (int*)(rt + 128 + 262144);

    hipMemsetAsync(rt, 0, 64, stream);  // counts + fill
    k_prep<<<dim3(32, 32, 16), 256, 0, stream>>>(W1, W2, w1t, w2t);
    k_gate<<<512, 256, 0, stream>>>(x, Wg, bg, xh, te, tw, counts);
    k_scan<<<1, 64, 0, stream>>>(counts, offs, fill);
    k_scatter<<<32, 256, 0, stream>>>(te, tw, offs, fill, ltok, lw, tslot);
    k_gemm<1><<<dim3(64, 32), 512, 0, stream>>>(xh, w1t, b1, counts, offs, ltok, nullptr, hb);
    k_gemm<2><<<dim3(64, 32), 512, 0, stream>>>(hb, w2t, b2, counts, offs, ltok, lw, yb);
    k_combine<<<8192, 256, 0, stream>>>(yb, tslot, out);
}

// Round 10
// 555.641 us; speedup vs baseline: 1.2172x; 1.1098x over previous
//
#include <hip/hip_runtime.h>
#include <hip/hip_bf16.h>
#include <cstdint>
#include <cstddef>

#define N_TOK 8192
#define DIM   2048
#define HID   2048
#define NE    8
#define ARENA 18432   // 16384 + 8*256 max padded rows

typedef _Float16 half8  __attribute__((ext_vector_type(8)));
typedef _Float16 half4v __attribute__((ext_vector_type(4)));
typedef float    floatx4 __attribute__((ext_vector_type(4)));

#define BARR  __builtin_amdgcn_s_barrier()
#define LGKM0 asm volatile("s_waitcnt lgkmcnt(0)" ::: "memory")
#define VMC0  asm volatile("s_waitcnt vmcnt(0)" ::: "memory")

__device__ inline void gload_lds16(const void* g, void* l) {
    __builtin_amdgcn_global_load_lds(
        (const __attribute__((address_space(1))) unsigned int*)g,
        (__attribute__((address_space(3))) unsigned int*)l, 16, 0, 0);
}

__device__ __forceinline__ floatx4 MF(half8 a, half8 b, floatx4 c) {
    return __builtin_amdgcn_mfma_f32_16x16x32_f16(a, b, c, 0, 0, 0);
}

// ---------------- fused W1+W2 [E][R][C] fp32 -> [E][C][R] fp16 ----------------
__global__ __launch_bounds__(256) void k_prep(const float* __restrict__ W1,
                                              const float* __restrict__ W2,
                                              _Float16* __restrict__ w1t,
                                              _Float16* __restrict__ w2t) {
    __shared__ float tile[64][65];
    int z = blockIdx.z;
    const float* in = (z < 8) ? W1 : W2;
    _Float16* out   = (z < 8) ? w1t : w2t;
    int e  = z & 7;
    int r0 = blockIdx.y * 64;
    int c0 = blockIdx.x * 64;
    int tc = threadIdx.x & 63, tr = threadIdx.x >> 6;
    const float* ip = in + ((size_t)e * 2048 + r0) * 2048 + c0;
#pragma unroll
    for (int i = 0; i < 16; i++)
        tile[tr + i * 4][tc] = ip[(size_t)(tr + i * 4) * 2048 + tc];
    __syncthreads();
    _Float16* op = out + ((size_t)e * 2048 + c0) * 2048 + r0;
#pragma unroll
    for (int i = 0; i < 16; i++) {
        int cc = tr + i * 4;
        op[(size_t)cc * 2048 + tc] = (_Float16)tile[tc][cc];
    }
}

// ---------------- gate: fp64-accum logits, top-2, softmax; fuses x->fp16 ----------------
__global__ __launch_bounds__(256) void k_gate(const float* __restrict__ x,
                                              const float* __restrict__ Wg,
                                              const float* __restrict__ bg,
                                              _Float16* __restrict__ xh,
                                              int* __restrict__ te, float* __restrict__ tw,
                                              int* __restrict__ counts) {
    __shared__ float wgs[NE * DIM]; // 64 KB, transposed [e][d]
    __shared__ int lcnt[NE];
    if (threadIdx.x < NE) lcnt[threadIdx.x] = 0;
    for (int i = threadIdx.x; i < NE * DIM; i += 256)
        wgs[(i & 7) * DIM + (i >> 3)] = Wg[i];
    __syncthreads();
    int wv = threadIdx.x >> 6, l = threadIdx.x & 63;
#pragma unroll 1
    for (int it = 0; it < 4; ++it) {
        int t = blockIdx.x * 16 + wv * 4 + it;
        const float* xr = x + (size_t)t * DIM;
        double acc[NE] = {0, 0, 0, 0, 0, 0, 0, 0};
#pragma unroll 2
        for (int i = 0; i < 8; i++) {
            int d0 = i * 256 + l * 4;
            float4 xv = *(const float4*)(xr + d0);
            half4v hv;
            hv[0] = (_Float16)xv.x; hv[1] = (_Float16)xv.y;
            hv[2] = (_Float16)xv.z; hv[3] = (_Float16)xv.w;
            *(half4v*)(xh + (size_t)t * DIM + d0) = hv;
#pragma unroll
            for (int e = 0; e < NE; e++) {
                float4 w4 = *(const float4*)(wgs + e * DIM + d0);
                acc[e] += (double)xv.x * w4.x + (double)xv.y * w4.y +
                          (double)xv.z * w4.z + (double)xv.w * w4.w;
            }
        }
#pragma unroll
        for (int e = 0; e < NE; e++) {
            double v = acc[e];
            v += __shfl_xor(v, 32, 64); v += __shfl_xor(v, 16, 64);
            v += __shfl_xor(v, 8, 64);  v += __shfl_xor(v, 4, 64);
            v += __shfl_xor(v, 2, 64);  v += __shfl_xor(v, 1, 64);
            acc[e] = v;
        }
        if (l == 0) {
            double best0 = -1e300, best1 = -1e300; int i0 = 0, i1 = 0;
#pragma unroll
            for (int e = 0; e < NE; e++) {
                double lg = acc[e] + (double)bg[e];
                if (lg > best0) { best1 = best0; i1 = i0; best0 = lg; i0 = e; }
                else if (lg > best1) { best1 = lg; i1 = e; }
            }
            float d  = expf((float)(best1 - best0));
            float w0 = 1.f / (1.f + d), w1 = d / (1.f + d);
            te[2 * t] = i0; te[2 * t + 1] = i1;
            tw[2 * t] = w0; tw[2 * t + 1] = w1;
            atomicAdd(&lcnt[i0], 1);
            atomicAdd(&lcnt[i1], 1);
        }
    }
    __syncthreads();
    if (threadIdx.x < NE) atomicAdd(&counts[threadIdx.x], lcnt[threadIdx.x]);
}

// ---------------- scan: padded arena offsets + job table ----------------
__global__ void k_scan(const int* __restrict__ counts, int* __restrict__ fill,
                       int* __restrict__ poff, int* __restrict__ cj) {
    if (threadIdx.x == 0 && blockIdx.x == 0) {
        int a = 0, jc = 0;
        for (int e = 0; e < NE; e++) {
            poff[e] = a; cj[e] = jc;
            int mb = (counts[e] + 255) >> 8;
            a  += mb << 8;
            jc += mb * 16;       // 16 n-tiles of 128
            fill[e] = 0;
        }
        poff[NE] = a; cj[NE] = jc;
    }
}

// ---------------- scatter tokens to padded expert arena ----------------
__global__ __launch_bounds__(256) void k_scatter(const int* __restrict__ te,
                                                 const float* __restrict__ tw,
                                                 const int* __restrict__ poff,
                                                 int* __restrict__ fill,
                                                 int* __restrict__ ltok,
                                                 float* __restrict__ lw,
                                                 int* __restrict__ tslot) {
    int t = blockIdx.x * blockDim.x + threadIdx.x;
    if (t >= N_TOK) return;
#pragma unroll
    for (int k = 0; k < 2; k++) {
        int e = te[2 * t + k];
        int p = atomicAdd(&fill[e], 1);
        int idx = poff[e] + p;
        ltok[idx] = t; lw[idx] = tw[2 * t + k]; tslot[2 * t + k] = idx;
    }
}

// ====== m97-style GEMM: BM=256, BN=128, BK=64, single-buffer, 2 blocks/CU ======
// 512 thr = 8 waves (4m x 2n); wave tile 64x64; acc[4][4] of 16x16x32_f16 (64 reg).
// LDS: As[256][64] + Bs[128][64] fp16 = 48 KB single buffer -> 2 blocks/CU
// (launch_bounds(512,4): 4 waves/SIMD). Co-resident blocks fill each other's
// drain/barrier stalls (m114) - no intra-block pipelining needed.
// Flat padded jobs: j -> (e via cumjobs, mb, nb); nb-inner => jobs j and j+16
// share the same B panel and land on the same XCD (id%8) -> L2 locality.
// XOR swizzle both-sides (rule 21): physical 16B chunk = logical ^ (row&7).
// kk-outer MFMA: 16 independent accumulators between dependent kk uses.

template<int LAYER>
__global__ __launch_bounds__(512, 4) void k_gemm(const _Float16* __restrict__ Ain,
                                                 const _Float16* __restrict__ Bt,
                                                 const float* __restrict__ bias,
                                                 const int* __restrict__ cj,
                                                 const int* __restrict__ poff,
                                                 const int* __restrict__ ltok,
                                                 const float* __restrict__ lw,
                                                 _Float16* __restrict__ Cout) {
    __shared__ _Float16 As[256 * 64];
    __shared__ _Float16 Bs[128 * 64];

    int j = blockIdx.x;
    if (j >= cj[NE]) return;
    int e = 0;
#pragma unroll
    for (int k = 0; k < NE - 1; k++) e += (j >= cj[k + 1]);
    int r  = j - cj[e];
    int m0 = poff[e] + (r >> 4) * 256;   // arena row base
    int n0 = (r & 15) * 128;

    int tid = threadIdx.x;
    int l = tid & 63;
    int wid = tid >> 6;
    int wm = wid >> 1, wn = wid & 1;     // 4m x 2n
    int lr = l & 15, lk = l >> 4;
    int rA = (wm * 64 + lr) * 64;
    int rB = (wn * 64 + lr) * 64;

    // staging: thread covers rows (tid>>3)+j*64, physical chunk tid&7;
    // global source column pre-swizzled so LDS chunk c holds logical c^(row&7).
    int sd = tid * 8;                    // == (tid>>3)*64 + (tid&7)*8
    size_t koff = (size_t)(((tid & 7) ^ ((tid >> 3) & 7)) * 8);

    const _Float16* aS[4];
#pragma unroll
    for (int q = 0; q < 4; q++) {
        int ar = m0 + (tid >> 3) + q * 64;
        if constexpr (LAYER == 1) {
            int tok = ltok[ar];
            aS[q] = Ain + (size_t)tok * DIM + koff;
        } else {
            aS[q] = Ain + (size_t)ar * HID + koff;
        }
    }
    const _Float16* bS[2];
#pragma unroll
    for (int q = 0; q < 2; q++)
        bS[q] = Bt + ((size_t)(e * 2048 + n0 + (tid >> 3) + q * 64)) * 2048 + koff;

    floatx4 acc[4][4];
#pragma unroll
    for (int m = 0; m < 4; m++)
#pragma unroll
        for (int n = 0; n < 4; n++) acc[m][n] = (floatx4){0.f, 0.f, 0.f, 0.f};

    // prologue: stage tile 0
#pragma unroll
    for (int q = 0; q < 4; q++) gload_lds16(aS[q], As + sd + q * 4096);
#pragma unroll
    for (int q = 0; q < 2; q++) gload_lds16(bS[q], Bs + sd + q * 4096);

#pragma unroll 1
    for (int t = 0; t < 32; ++t) {
        VMC0;    // staged tile t landed (co-resident block covers this drain)
        BARR;
#pragma unroll
        for (int kk = 0; kk < 2; kk++) {
            int cbo = ((kk * 4 + lk) ^ (lr & 7)) * 8;
            half8 a[4], b[4];
#pragma unroll
            for (int fm = 0; fm < 4; fm++)
                a[fm] = *(const half8*)(As + rA + fm * 1024 + cbo);
#pragma unroll
            for (int fn = 0; fn < 4; fn++)
                b[fn] = *(const half8*)(Bs + rB + fn * 1024 + cbo);
#pragma unroll
            for (int fn = 0; fn < 4; fn++)
#pragma unroll
                for (int fm = 0; fm < 4; fm++)
                    acc[fm][fn] = MF(a[fm], b[fn], acc[fm][fn]);
        }
        LGKM0;   // own reads retired
        BARR;    // all waves done reading -> safe to overwrite buffer
        if (t < 31) {
#pragma unroll
            for (int q = 0; q < 4; q++)
                gload_lds16(aS[q] + (size_t)(t + 1) * 64, As + sd + q * 4096);
#pragma unroll
            for (int q = 0; q < 2; q++)
                gload_lds16(bS[q] + (size_t)(t + 1) * 64, Bs + sd + q * 4096);
        }
    }

    // epilogue (no row guards - arena is padded)
#pragma unroll
    for (int fm = 0; fm < 4; fm++) {
        int row0 = m0 + wm * 64 + fm * 16 + lk * 4;
#pragma unroll
        for (int fn = 0; fn < 4; fn++) {
            int col = n0 + wn * 64 + fn * 16 + lr;
            float bv = bias[e * 2048 + col];
#pragma unroll
            for (int rr = 0; rr < 4; rr++) {
                int row = row0 + rr;
                float v = acc[fm][fn][rr] + bv;
                if constexpr (LAYER == 1) {
                    v = v > 0.f ? v : 0.f;
                } else {
                    v *= lw[row];
                }
                Cout[(size_t)row * HID + col] = (_Float16)v;
            }
        }
    }
}

// ---------------- combine the two weighted expert rows per token ----------------
__global__ __launch_bounds__(256) void k_combine(const _Float16* __restrict__ yb,
                                                 const int* __restrict__ tslot,
                                                 float* __restrict__ out) {
    int t = blockIdx.x;
    int s0 = tslot[2 * t], s1 = tslot[2 * t + 1];
    int c = threadIdx.x * 8;
    half8 y0 = *(const half8*)&yb[(size_t)s0 * HID + c];
    half8 y1 = *(const half8*)&yb[(size_t)s1 * HID + c];
    float* op = out + (size_t)t * HID + c;
    float4 o;
    o.x = (float)y0[0] + (float)y1[0];
    o.y = (float)y0[1] + (float)y1[1];
    o.z = (float)y0[2] + (float)y1[2];
    o.w = (float)y0[3] + (float)y1[3];
    *(float4*)(op) = o;
    o.x = (float)y0[4] + (float)y1[4];
    o.y = (float)y0[5] + (float)y1[5];
    o.z = (float)y0[6] + (float)y1[6];
    o.w = (float)y0[7] + (float)y1[7];
    *(float4*)(op + 4) = o;
}

extern "C" void kernel_launch(void* const* d_in, const int* in_sizes, int n_in,
                              void* d_out, int out_size, void* d_ws, size_t ws_size,
                              hipStream_t stream) {
    const float* x  = (const float*)d_in[0];
    const float* Wg = (const float*)d_in[1];
    const float* bg = (const float*)d_in[2];
    const float* W1 = (const float*)d_in[3];
    const float* b1 = (const float*)d_in[4];
    const float* W2 = (const float*)d_in[5];
    const float* b2 = (const float*)d_in[6];
    float* out = (float*)d_out;

    // ws layout (yb aliases xh+w1t, both dead by gemm2):
    //   [0,33.5M)    xh        (fp16 8192x2048)        | yb arena (fp16 18432x2048 = 75.5M)
    //   [33.5M,100.6M)  w1t    (fp16 8x2048x2048)      |   ... yb spans into w1t region
    //   [100.6M,167.8M) w2t
    //   [167.8M,243.3M) hb arena (fp16 18432x2048)
    //   [243.3M, ...)   tables
    char* ws = (char*)d_ws;
    _Float16* xh  = (_Float16*)(ws);
    _Float16* yb  = (_Float16*)(ws);                        // alias: safe, see order
    _Float16* w1t = (_Float16*)(ws + 33554432ULL);
    _Float16* w2t = (_Float16*)(ws + 100663296ULL);
    _Float16* hb  = (_Float16*)(ws + 167772160ULL);
    char* rt = ws + 167772160ULL + (size_t)ARENA * HID * 2; // 243,269,632
    int*   counts = (int*)(rt);              // 8
    int*   fill   = (int*)(rt + 32);         // 8
    int*   poff   = (int*)(rt + 64);         // 9
    int*   cj     = (int*)(rt + 128);        // 9
    int*   te     = (int*)(rt + 192);        // 16384
    float* tw     = (float*)(rt + 192 + 65536);
    int*   tslot  = (int*)(rt + 192 + 131072);
    int*   ltok   = (int*)(rt + 192 + 196608);              // ARENA ints
    float* lw     = (float*)(rt + 192 + 196608 + 73728);    // ARENA floats

    hipMemsetAsync(rt, 0, 64, stream);                   // counts + fill
    hipMemsetAsync(ltok, 0, (size_t)ARENA * 8, stream);  // ltok + lw pads = 0
    k_prep<<<dim3(32, 32, 16), 256, 0, stream>>>(W1, W2, w1t, w2t);
    k_gate<<<512, 256, 0, stream>>>(x, Wg, bg, xh, te, tw, counts);
    k_scan<<<1, 64, 0, stream>>>(counts, fill, poff, cj);
    k_scatter<<<32, 256, 0, stream>>>(te, tw, poff, fill, ltok, lw, tslot);
    k_gemm<1><<<dim3(1136), 512, 0, stream>>>(xh, w1t, b1, cj, poff, ltok, nullptr, hb);
    k_gemm<2><<<dim3(1136), 512, 0, stream>>>(hb, w2t, b2, cj, poff, ltok, lw, yb);
    k_combine<<<8192, 256, 0, stream>>>(yb, tslot, out);
}